// Round 3
// baseline (10046.308 us; speedup 1.0000x reference)
//
#include <hip/hip_runtime.h>
#include <math.h>
#include <stdint.h>

#define B 128
#define S 512
#define V 6000
#define E 100
#define H 256
#define G4 1024   /* 4*H */
#define T 9

/* workspace byte offsets (all 256-aligned) */
#define OFF_WT_F   0u
#define OFF_WT_B   (1u<<20)
#define OFF_PEMB_F (2u<<20)
#define PEMB_BYTES (V*G4*4u)              /* 24,576,000 */
#define OFF_PEMB_B (OFF_PEMB_F + PEMB_BYTES)
#define OFF_EM     (OFF_PEMB_B + PEMB_BYTES)   /* 51,249,152 */
#define EM_BYTES   (B*S*T*4u)             /* 2,359,296 */
#define OFF_BP     (OFF_EM + EM_BYTES)
#define BP_BYTES   ((S-1)*B*16u)          /* 1,046,528 */
#define OFF_LT     (OFF_BP + BP_BYTES)
#define OFF_PT     (OFF_LT + 512u)
#define OFF_HPUB   (OFF_PT + B*S*4u)      /* 32 clusters * 2 parity * 2048 floats = 512 KB */
#define OFF_CNT    (OFF_HPUB + 32u*2u*2048u*4u)   /* 32 * 512 ints = 64 KB */

__device__ __forceinline__ float sigf(float x) { return 1.0f / (1.0f + expf(-x)); }

__device__ __forceinline__ float2 pkfma(float s, float2 h, float2 a) {
    return make_float2(fmaf(s, h.x, a.x), fmaf(s, h.y, a.y));
}

/* W_hh [4H][H] row-major  ->  wt[k*1024 + j*4 + q] = W_hh[q*256+j][k] */
__global__ __launch_bounds__(256) void k_transpose(const float* __restrict__ whf,
                                                   const float* __restrict__ whb,
                                                   char* __restrict__ ws) {
    int tid = blockIdx.x * 256 + threadIdx.x;
    int d   = tid >> 18;
    int idx = tid & 262143;
    int q = idx & 3, j = (idx >> 2) & 255, k = idx >> 10;
    const float* w  = d ? whb : whf;
    float* wt = (float*)(ws + (d ? OFF_WT_B : OFF_WT_F));
    wt[idx] = w[(q * H + j) * H + k];
}

/* em init to mlp_b; cluster counters to 0 */
__global__ __launch_bounds__(256) void k_zero(const float* __restrict__ mlpb,
                                              char* __restrict__ ws) {
    int i = blockIdx.x * 256 + threadIdx.x;      /* 2304*256 = 589824 */
    float* em = (float*)(ws + OFF_EM);
    int* cnt  = (int*)(ws + OFF_CNT);
    if (i < B * S * T) em[i] = mlpb[i % T];
    if (i < 32 * 512) cnt[i] = 0;
}

/* pemb[v][g] = bias[g] + sum_e emb[v][e] * W_ih[g][e],  g = q*256 + j */
__global__ __launch_bounds__(256) void k_pemb(const float* __restrict__ emb,
                                              const float* __restrict__ wf, const float* __restrict__ bf,
                                              const float* __restrict__ wb, const float* __restrict__ bb,
                                              char* __restrict__ ws) {
    int blk = blockIdx.x;                   /* 0..749 */
    int d   = blk >= 375;
    int vb  = d ? blk - 375 : blk;
    const float* W    = d ? wb : wf;
    const float* bias = d ? bb : bf;
    float* pe = (float*)(ws + (d ? OFF_PEMB_B : OFF_PEMB_F));

    __shared__ float es[16 * E];
    for (int i = threadIdx.x; i < 16 * E; i += 256) es[i] = emb[vb * 16 * E + i];
    __syncthreads();

    int j = threadIdx.x;
    float acc[4][16];
    #pragma unroll
    for (int q = 0; q < 4; q++) {
        float bq = bias[q * H + j];
        #pragma unroll
        for (int v = 0; v < 16; v++) acc[q][v] = bq;
    }
    for (int e = 0; e < E; e++) {
        float w0 = W[(0 * H + j) * E + e];
        float w1 = W[(1 * H + j) * E + e];
        float w2 = W[(2 * H + j) * E + e];
        float w3 = W[(3 * H + j) * E + e];
        #pragma unroll
        for (int v = 0; v < 16; v++) {
            float x = es[v * E + e];
            acc[0][v] += w0 * x; acc[1][v] += w1 * x;
            acc[2][v] += w2 * x; acc[3][v] += w3 * x;
        }
    }
    for (int v = 0; v < 16; v++)
        #pragma unroll
        for (int q = 0; q < 4; q++)
            pe[(vb * 16 + v) * G4 + q * H + j] = acc[q][v];
}

/* Cluster-of-8 LSTM: 256 blocks x 512 threads, 1 block/CU.
   Block = (cluster c = blk&31, slice sl = blk>>5). Cluster: dir = c>>4,
   batches b0..b0+7 (b0 = (c&15)*8). Block owns j-units [sl*32, sl*32+32),
   W-slice (128 KB) in VGPRs (64/thread). Per step: register FMA over the
   block's thread k-slices, LDS-atomic gate reduce, activation, h publish via
   agent-scope atomics + flag counter (parity double buffer). */
__global__ __launch_bounds__(512, 2) void k_lstm(const int* __restrict__ data,
                                                 const float* __restrict__ mlpW,
                                                 char* __restrict__ ws) {
    int blk = blockIdx.x;
    int c = blk & 31, sl = blk >> 5;
    int d = c >> 4, b0 = (c & 15) << 3;
    const float4* wt4 = (const float4*)(ws + (d ? OFF_WT_B : OFF_WT_F));
    const float*  pe  = (const float*)(ws + (d ? OFF_PEMB_B : OFF_PEMB_F));
    float* em   = (float*)(ws + OFF_EM);
    float* hpub = (float*)(ws + OFF_HPUB) + (size_t)c * 2 * 2048;
    int*   cnt  = (int*)(ws + OFF_CNT) + c * 512;

    __shared__ float hs[2048];       /* h_prev: [k 256][b 8] */
    __shared__ float gate[1024];     /* [q 4][b 8][j 32] */
    __shared__ int   toks[8 * S];

    int tid = threadIdx.x;
    int jl = tid & 31;
    int ks = tid >> 5;               /* 0..15: k-slice of 16 */
    int ba = (tid >> 5) & 7;         /* batch role (init/activation) */
    int gh = tid >> 8;               /* gate-half role (init) */

    /* W-slice -> registers: thread (jl, ks) holds w4[kk] for k = ks*16+kk */
    float4 w4[16];
    {
        const float4* wp = wt4 + (size_t)(ks * 16) * 256 + sl * 32 + jl;
        #pragma unroll
        for (int kk = 0; kk < 16; kk++) w4[kk] = wp[(size_t)kk * 256];
    }
    float mwreg[T];
    if (tid < 256) {
        #pragma unroll
        for (int t = 0; t < T; t++) mwreg[t] = mlpW[t * (2 * H) + d * H + sl * 32 + jl];
    }
    for (int i = tid; i < 8 * S; i += 512) toks[i] = data[(b0 + (i >> 9)) * S + (i & 511)];
    #pragma unroll
    for (int i = 0; i < 4; i++) hs[tid * 4 + i] = 0.0f;
    float cst = 0.0f;
    __syncthreads();

    /* prefetch pemb gate slices for step 0 */
    float pf0, pf1;
    {
        int sp0 = d ? (S - 1) : 0;
        int tok = toks[ba * S + sp0];
        const float* pr = pe + (size_t)tok * G4 + sl * 32 + jl;
        pf0 = pr[(gh * 2 + 0) * 256];
        pf1 = pr[(gh * 2 + 1) * 256];
    }

    for (int ss = 0; ss < S; ss++) {
        int sp = d ? (S - 1 - ss) : ss;
        /* phase 1: gate <- pemb (prefetched), issue next prefetch */
        gate[((gh * 2 + 0) * 8 + ba) * 32 + jl] = pf0;
        gate[((gh * 2 + 1) * 8 + ba) * 32 + jl] = pf1;
        if (ss + 1 < S) {
            int spn = d ? (S - 2 - ss) : (ss + 1);
            int tokn = toks[ba * S + spn];
            const float* pr = pe + (size_t)tokn * G4 + sl * 32 + jl;
            pf0 = pr[(gh * 2 + 0) * 256];
            pf1 = pr[(gh * 2 + 1) * 256];
        }
        __syncthreads();   /* A: gate init + hs ready */

        /* phase 2: register-W FMA over 16 k's, 8 batches packed as 4 float2 */
        float2 a[4][4];
        #pragma unroll
        for (int q = 0; q < 4; q++)
            #pragma unroll
            for (int p = 0; p < 4; p++) a[q][p] = make_float2(0.f, 0.f);
        const float2* hsp = (const float2*)hs + (ks << 6);
        #pragma unroll
        for (int kk = 0; kk < 16; kk++) {
            float4 wv = w4[kk];
            float2 h0 = hsp[kk * 4 + 0];
            float2 h1 = hsp[kk * 4 + 1];
            float2 h2 = hsp[kk * 4 + 2];
            float2 h3 = hsp[kk * 4 + 3];
            a[0][0] = pkfma(wv.x, h0, a[0][0]); a[0][1] = pkfma(wv.x, h1, a[0][1]);
            a[0][2] = pkfma(wv.x, h2, a[0][2]); a[0][3] = pkfma(wv.x, h3, a[0][3]);
            a[1][0] = pkfma(wv.y, h0, a[1][0]); a[1][1] = pkfma(wv.y, h1, a[1][1]);
            a[1][2] = pkfma(wv.y, h2, a[1][2]); a[1][3] = pkfma(wv.y, h3, a[1][3]);
            a[2][0] = pkfma(wv.z, h0, a[2][0]); a[2][1] = pkfma(wv.z, h1, a[2][1]);
            a[2][2] = pkfma(wv.z, h2, a[2][2]); a[2][3] = pkfma(wv.z, h3, a[2][3]);
            a[3][0] = pkfma(wv.w, h0, a[3][0]); a[3][1] = pkfma(wv.w, h1, a[3][1]);
            a[3][2] = pkfma(wv.w, h2, a[3][2]); a[3][3] = pkfma(wv.w, h3, a[3][3]);
        }
        /* pre-reduce ks pairs via xor-32, then half-lanes LDS-atomic into gate */
        #pragma unroll
        for (int q = 0; q < 4; q++)
            #pragma unroll
            for (int p = 0; p < 4; p++) {
                a[q][p].x += __shfl_xor(a[q][p].x, 32, 64);
                a[q][p].y += __shfl_xor(a[q][p].y, 32, 64);
            }
        if ((tid & 32) == 0) {
            #pragma unroll
            for (int q = 0; q < 4; q++)
                #pragma unroll
                for (int p = 0; p < 4; p++) {
                    atomicAdd(&gate[(q * 8 + 2 * p + 0) * 32 + jl], a[q][p].x);
                    atomicAdd(&gate[(q * 8 + 2 * p + 1) * 32 + jl], a[q][p].y);
                }
        }
        __syncthreads();   /* B: gates complete */

        /* phase 3: activation + emission + publish (threads 0..255: (jl, ba)) */
        if (tid < 256) {
            float g0 = gate[(0 * 8 + ba) * 32 + jl];
            float g1 = gate[(1 * 8 + ba) * 32 + jl];
            float g2 = gate[(2 * 8 + ba) * 32 + jl];
            float g3 = gate[(3 * 8 + ba) * 32 + jl];
            float ig = sigf(g0), fg = sigf(g1), gg = tanhf(g2), og = sigf(g3);
            cst = fg * cst + ig * gg;
            float hn = og * tanhf(cst);

            float ev[T];
            #pragma unroll
            for (int t = 0; t < T; t++) {
                float v = hn * mwreg[t];
                v += __shfl_xor(v, 16, 64); v += __shfl_xor(v, 8, 64);
                v += __shfl_xor(v, 4, 64);  v += __shfl_xor(v, 2, 64);
                v += __shfl_xor(v, 1, 64);
                ev[t] = v;
            }
            if (jl == 0) {
                float* emrow = em + ((size_t)(b0 + ba) * S + sp) * T;
                #pragma unroll
                for (int t = 0; t < T; t++) atomicAdd(emrow + t, ev[t]);
            }
            if (ss < S - 1)
                __hip_atomic_store(&hpub[(ss & 1) * 2048 + (sl * 32 + jl) * 8 + ba], hn,
                                   __ATOMIC_RELAXED, __HIP_MEMORY_SCOPE_AGENT);
        }

        if (ss < S - 1) {
            __syncthreads();   /* C: drains vmcnt -> publishes visible (sc0sc1 stores) */
            if (tid == 0) {
                __hip_atomic_fetch_add(&cnt[ss], 1, __ATOMIC_RELEASE, __HIP_MEMORY_SCOPE_AGENT);
                while (__hip_atomic_load(&cnt[ss], __ATOMIC_ACQUIRE, __HIP_MEMORY_SCOPE_AGENT) < 8)
                    __builtin_amdgcn_s_sleep(8);
            }
            __syncthreads();   /* D: all threads see flag done */
            const float* hp = hpub + (ss & 1) * 2048;
            #pragma unroll
            for (int i = 0; i < 4; i++)
                hs[tid * 4 + i] = __hip_atomic_load(hp + tid * 4 + i,
                                                    __ATOMIC_RELAXED, __HIP_MEMORY_SCOPE_AGENT);
            /* barrier A at next loop top orders hs for FMA readers */
        }
    }
}

/* Viterbi forward: one wave per batch, lane t = tag. Strict-> ascending scan
   matches jnp.argmax first-index tie-breaking. */
__global__ __launch_bounds__(64) void k_vit(const int* __restrict__ data,
                                            const float* __restrict__ strans,
                                            const float* __restrict__ trans,
                                            const float* __restrict__ etrans,
                                            float* __restrict__ out,
                                            char* __restrict__ ws) {
    int b = blockIdx.x, t = threadIdx.x;
    const float* em = (const float*)(ws + OFF_EM);
    char* bp = ws + OFF_BP;
    int*  lt = (int*)(ws + OFF_LT);
    bool act = t < T;

    float trp[T];
    if (act) {
        #pragma unroll
        for (int p = 0; p < T; p++) trp[p] = trans[p * T + t];
    }
    float score = -1e30f;
    if (act) score = strans[t] + em[(b * S) * T + t];

    for (int s = 1; s < S; s++) {
        float e = 0.0f;
        if (act) e = em[(b * S + s) * T + t];
        float best = __shfl(score, 0, 64) + trp[0];
        int bpi = 0;
        #pragma unroll
        for (int p = 1; p < T; p++) {
            float cand = __shfl(score, p, 64) + trp[p];
            if (cand > best) { best = cand; bpi = p; }
        }
        int m = data[b * S + s] != 0;
        if (act) {
            score = m ? (best + e) : score;
            bp[((size_t)(s - 1) * B + b) * 16 + t] = (char)bpi;
        }
    }
    float fin = act ? score + etrans[t] : -1e30f;
    float bv = __shfl(fin, 0, 64);
    int bi = 0;
    #pragma unroll
    for (int p = 1; p < T; p++) {
        float v = __shfl(fin, p, 64);
        if (v > bv) { bv = v; bi = p; }
    }
    if (t == 0) { out[B * S + b] = bv; lt[b] = bi; }
}

/* Backtrack: thread = batch; bp row address is tag-independent -> pipelined loads */
__global__ __launch_bounds__(128) void k_back(const int* __restrict__ data, char* __restrict__ ws) {
    int b = threadIdx.x;
    const int4* bp4 = (const int4*)(ws + OFF_BP);
    const int*  lt  = (const int*)(ws + OFF_LT);
    int* pt = (int*)(ws + OFF_PT);
    int tag = lt[b];
    pt[(S - 1) * B + b] = tag;
    for (int p = S - 2; p >= 0; p--) {
        int4 r = bp4[(size_t)p * B + b];
        int m = data[b * S + p + 1] != 0;
        unsigned w = (unsigned)(tag < 8 ? (tag < 4 ? r.x : r.y) : r.z);
        int nt = (int)((w >> ((tag & 3) * 8)) & 0xff);
        tag = m ? nt : tag;
        pt[p * B + b] = tag;
    }
}

/* paths -> float output with mask zeroing */
__global__ __launch_bounds__(256) void k_fin(const int* __restrict__ data,
                                             float* __restrict__ out,
                                             const char* __restrict__ ws) {
    int tid = blockIdx.x * 256 + threadIdx.x;   /* 65536 */
    const int* pt = (const int*)(ws + OFF_PT);
    int b = tid >> 9, p = tid & 511;
    out[tid] = (data[tid] != 0) ? (float)pt[p * B + b] : 0.0f;
}

extern "C" void kernel_launch(void* const* d_in, const int* in_sizes, int n_in,
                              void* d_out, int out_size, void* d_ws, size_t ws_size,
                              hipStream_t stream) {
    const int*   data = (const int*)d_in[0];
    /* d_in[1] = mask (bool) — unused; mask == (data != 0) */
    const float* emb  = (const float*)d_in[2];
    const float* wihf = (const float*)d_in[3];
    const float* whhf = (const float*)d_in[4];
    const float* bf   = (const float*)d_in[5];
    const float* wihb = (const float*)d_in[6];
    const float* whhb = (const float*)d_in[7];
    const float* bb   = (const float*)d_in[8];
    const float* mlpW = (const float*)d_in[9];
    const float* mlpb = (const float*)d_in[10];
    const float* st   = (const float*)d_in[11];
    const float* tr   = (const float*)d_in[12];
    const float* et   = (const float*)d_in[13];
    float* out = (float*)d_out;
    char*  ws  = (char*)d_ws;

    hipLaunchKernelGGL(k_zero,      dim3(2304), dim3(256), 0, stream, mlpb, ws);
    hipLaunchKernelGGL(k_transpose, dim3(2048), dim3(256), 0, stream, whhf, whhb, ws);
    hipLaunchKernelGGL(k_pemb,      dim3(750),  dim3(256), 0, stream, emb, wihf, bf, wihb, bb, ws);
    hipLaunchKernelGGL(k_lstm,      dim3(256),  dim3(512), 0, stream, data, mlpW, ws);
    hipLaunchKernelGGL(k_vit,       dim3(128),  dim3(64),  0, stream, data, st, tr, et, out, ws);
    hipLaunchKernelGGL(k_back,      dim3(1),    dim3(128), 0, stream, data, ws);
    hipLaunchKernelGGL(k_fin,       dim3(256),  dim3(256), 0, stream, data, out, ws);
}

// Round 4
// 7965.310 us; speedup vs baseline: 1.2613x; 1.2613x over previous
//
#include <hip/hip_runtime.h>
#include <math.h>
#include <stdint.h>

#define B 128
#define S 512
#define V 6000
#define E 100
#define H 256
#define G4 1024   /* 4*H */
#define T 9
#define NCL 64    /* clusters = 2 dir x 32 batch-groups */
#define NSL 4     /* slices (blocks) per cluster */
#define NB 4      /* batches per cluster */

/* workspace byte offsets (256-aligned) */
#define OFF_PEMB_F 0u
#define PEMB_BYTES (V*G4*4u)                    /* 24,576,000 */
#define OFF_PEMB_B (OFF_PEMB_F + PEMB_BYTES)
#define OFF_EMF    (OFF_PEMB_B + PEMB_BYTES)    /* 49,152,000 */
#define EM_BYTES   (B*S*T*4u)                   /* 2,359,296 */
#define OFF_EMB    (OFF_EMF + EM_BYTES)
#define OFF_BP     (OFF_EMB + EM_BYTES)         /* 53,870,592 */
#define BP_BYTES   ((S-1)*B*16u)                /* 1,046,528 */
#define OFF_LT     (OFF_BP + BP_BYTES)
#define OFF_PT     (OFF_LT + 512u)
#define OFF_HPUB   (OFF_PT + B*S*4u)            /* 64*2*4*256 floats = 524,288 B */
#define OFF_CNT    (OFF_HPUB + 524288u)         /* 64*512*4 ints  = 524,288 B */

__device__ __forceinline__ float sigf(float x) { return 1.0f / (1.0f + expf(-x)); }

__device__ __forceinline__ float2 pkfma(float s, float2 h, float2 a) {
    return make_float2(fmaf(s, h.x, a.x), fmaf(s, h.y, a.y));
}

/* flag counters -> 0 (re-poisoned to 0xAA each launch) */
__global__ __launch_bounds__(256) void k_zero(char* __restrict__ ws) {
    int i = blockIdx.x * 256 + threadIdx.x;     /* 512*256 = 131072 */
    ((int*)(ws + OFF_CNT))[i] = 0;
}

/* pemb[v][g4] = bias[g4] + sum_e emb[v][e] * W_ih[g4][e],  g4 = q*H + j */
__global__ __launch_bounds__(256) void k_pemb(const float* __restrict__ emb,
                                              const float* __restrict__ wf, const float* __restrict__ bf,
                                              const float* __restrict__ wb, const float* __restrict__ bb,
                                              char* __restrict__ ws) {
    int blk = blockIdx.x;                   /* 0..749 */
    int d   = blk >= 375;
    int vb  = d ? blk - 375 : blk;
    const float* W    = d ? wb : wf;
    const float* bias = d ? bb : bf;
    float* pe = (float*)(ws + (d ? OFF_PEMB_B : OFF_PEMB_F));

    __shared__ float es[16 * E];
    for (int i = threadIdx.x; i < 16 * E; i += 256) es[i] = emb[vb * 16 * E + i];
    __syncthreads();

    int j = threadIdx.x;
    float acc[4][16];
    #pragma unroll
    for (int q = 0; q < 4; q++) {
        float bq = bias[q * H + j];
        #pragma unroll
        for (int v = 0; v < 16; v++) acc[q][v] = bq;
    }
    for (int e = 0; e < E; e++) {
        float w0 = W[(0 * H + j) * E + e];
        float w1 = W[(1 * H + j) * E + e];
        float w2 = W[(2 * H + j) * E + e];
        float w3 = W[(3 * H + j) * E + e];
        #pragma unroll
        for (int v = 0; v < 16; v++) {
            float x = es[v * E + e];
            acc[0][v] += w0 * x; acc[1][v] += w1 * x;
            acc[2][v] += w2 * x; acc[3][v] += w3 * x;
        }
    }
    for (int v = 0; v < 16; v++)
        #pragma unroll
        for (int q = 0; q < 4; q++)
            pe[(vb * 16 + v) * G4 + q * H + j] = acc[q][v];
}

/* Cluster-of-4 LSTM. 256 blocks x 256 threads, 1 block/CU (VGPR-forced).
   blk: sl = blk>>6 (0..3), c = blk&63; cluster blocks {c, c+64, c+128, c+192}
   (stride 64 = same XCD under round-robin dispatch heuristic).
   Cluster c: dir = c>>5, batches b0 = (c&31)*4 .. +3.
   Thread tid: gate-unit g4 = (tid>>6)*H + sl*64 + (tid&63); its 256 W_hh
   weights live in 64 float4 VGPRs (no W memory traffic in the loop).
   Per step: gates = pemb(tok) + W.h (h broadcast from LDS, 4 batches as
   2x float2 pk-fma), LDS gate exchange, activation (thread role (b,j)),
   publish 64x4 h floats agent-scope, per-slice flag store, poll 4 flags,
   rebuild LDS h. Emissions (tag-subset per slice) plain-stored from full h. */
__global__ __launch_bounds__(256, 1) void k_lstm(const int* __restrict__ data,
                                                 const float* __restrict__ whhf,
                                                 const float* __restrict__ whhb,
                                                 const float* __restrict__ mlpW,
                                                 char* __restrict__ ws) {
    int blk = blockIdx.x;
    int sl = blk >> 6, c = blk & 63;
    int d = c >> 5, b0 = (c & 31) << 2;
    const float* pe = (const float*)(ws + (d ? OFF_PEMB_B : OFF_PEMB_F));
    float* emdst = (float*)(ws + (d ? OFF_EMB : OFF_EMF));
    float* hpub  = (float*)(ws + OFF_HPUB);
    int*   cnt   = (int*)(ws + OFF_CNT);

    __shared__ float4 hs4[H];          /* h[k] for 4 batches */
    __shared__ float  gbuf[4][64][4];  /* [q][jq][b] */
    float* hsf = (float*)hs4;

    int tid = threadIdx.x;
    int q  = tid >> 6, jq = tid & 63;
    int bq = tid >> 6, l  = tid & 63;          /* activation/emission roles */
    int g4 = q * H + sl * 64 + jq;

    /* W row -> 64 float4 registers */
    const float* whh = d ? whhb : whhf;
    float4 wreg[64];
    {
        const float4* wrow = (const float4*)(whh + (size_t)g4 * H);
        #pragma unroll
        for (int i = 0; i < 64; i++) wreg[i] = wrow[i];
    }
    /* emission weights for this slice's tag subset */
    int nt = (sl == 0) ? 3 : 2;
    int t0 = (sl == 0) ? 0 : (2 * sl + 1);
    float mwreg[3][4];
    #pragma unroll
    for (int i = 0; i < 3; i++)
        if (i < nt)
            #pragma unroll
            for (int jj = 0; jj < 4; jj++)
                mwreg[i][jj] = mlpW[(t0 + i) * (2 * H) + d * H + jj * 64 + l];

    /* zero h, c */
    hs4[tid] = make_float4(0.f, 0.f, 0.f, 0.f);
    float cst = 0.0f;

    /* prefetch pemb for step 0 */
    float pf0, pf1, pf2, pf3;
    {
        int sp0 = d ? (S - 1) : 0;
        pf0 = pe[(size_t)data[(b0 + 0) * S + sp0] * G4 + g4];
        pf1 = pe[(size_t)data[(b0 + 1) * S + sp0] * G4 + g4];
        pf2 = pe[(size_t)data[(b0 + 2) * S + sp0] * G4 + g4];
        pf3 = pe[(size_t)data[(b0 + 3) * S + sp0] * G4 + g4];
    }

    for (int ss = 0; ss < S; ss++) {
        int sp = d ? (S - 1 - ss) : ss;
        __syncthreads();   /* A: hs4 coherent (init or rebuilt) */

        float2 a01 = make_float2(pf0, pf1);
        float2 a23 = make_float2(pf2, pf3);
        if (ss + 1 < S) {
            int spn = d ? (S - 2 - ss) : (ss + 1);
            pf0 = pe[(size_t)data[(b0 + 0) * S + spn] * G4 + g4];
            pf1 = pe[(size_t)data[(b0 + 1) * S + spn] * G4 + g4];
            pf2 = pe[(size_t)data[(b0 + 2) * S + spn] * G4 + g4];
            pf3 = pe[(size_t)data[(b0 + 3) * S + spn] * G4 + g4];
        }

        /* emission for PREVIOUS step (full h is in hs4) */
        if (ss > 0) {
            int spe = d ? (S - ss) : (ss - 1);
            float h0 = hsf[(l +   0) * 4 + bq];
            float h1 = hsf[(l +  64) * 4 + bq];
            float h2 = hsf[(l + 128) * 4 + bq];
            float h3 = hsf[(l + 192) * 4 + bq];
            #pragma unroll
            for (int i = 0; i < 3; i++) {
                if (i < nt) {
                    float v = h0 * mwreg[i][0] + h1 * mwreg[i][1]
                            + h2 * mwreg[i][2] + h3 * mwreg[i][3];
                    v += __shfl_xor(v, 32, 64); v += __shfl_xor(v, 16, 64);
                    v += __shfl_xor(v, 8, 64);  v += __shfl_xor(v, 4, 64);
                    v += __shfl_xor(v, 2, 64);  v += __shfl_xor(v, 1, 64);
                    if (l == 0)
                        emdst[((size_t)(b0 + bq) * S + spe) * T + (t0 + i)] = v;
                }
            }
        }

        /* gates: a += W.h, k ascending (bit-compatible chain per gate) */
        #pragma unroll
        for (int kk = 0; kk < 64; kk++) {
            float4 w = wreg[kk];
            float4 h0 = hs4[4 * kk + 0];
            float4 h1 = hs4[4 * kk + 1];
            float4 h2 = hs4[4 * kk + 2];
            float4 h3 = hs4[4 * kk + 3];
            a01 = pkfma(w.x, make_float2(h0.x, h0.y), a01);
            a23 = pkfma(w.x, make_float2(h0.z, h0.w), a23);
            a01 = pkfma(w.y, make_float2(h1.x, h1.y), a01);
            a23 = pkfma(w.y, make_float2(h1.z, h1.w), a23);
            a01 = pkfma(w.z, make_float2(h2.x, h2.y), a01);
            a23 = pkfma(w.z, make_float2(h2.z, h2.w), a23);
            a01 = pkfma(w.w, make_float2(h3.x, h3.y), a01);
            a23 = pkfma(w.w, make_float2(h3.z, h3.w), a23);
        }
        *(float4*)&gbuf[q][jq][0] = make_float4(a01.x, a01.y, a23.x, a23.y);
        __syncthreads();   /* B: gates exchanged */

        /* activation: thread (bq, l) owns (batch b0+bq, unit j = sl*64+l) */
        float gi = gbuf[0][l][bq];
        float gf = gbuf[1][l][bq];
        float gg = gbuf[2][l][bq];
        float go = gbuf[3][l][bq];
        float ig = sigf(gi), fg = sigf(gf), tg = tanhf(gg), og = sigf(go);
        cst = fg * cst + ig * tg;
        float hn = og * tanhf(cst);

        int par = ss & 1;
        hsf[(sl * 64 + l) * 4 + bq] = hn;   /* own slice into LDS */
        __hip_atomic_store(&hpub[((c * 2 + par) * NSL + sl) * 256 + bq * 64 + l], hn,
                           __ATOMIC_RELAXED, __HIP_MEMORY_SCOPE_AGENT);

        __syncthreads();   /* C: all publishes issued+drained before flag */
        int* slots = cnt + (c * S + ss) * 4;
        if (tid == 0) {
            __hip_atomic_store(&slots[sl], 1, __ATOMIC_RELEASE, __HIP_MEMORY_SCOPE_AGENT);
            for (;;) {
                int s0 = __hip_atomic_load(&slots[0], __ATOMIC_RELAXED, __HIP_MEMORY_SCOPE_AGENT);
                int s1 = __hip_atomic_load(&slots[1], __ATOMIC_RELAXED, __HIP_MEMORY_SCOPE_AGENT);
                int s2 = __hip_atomic_load(&slots[2], __ATOMIC_RELAXED, __HIP_MEMORY_SCOPE_AGENT);
                int s3 = __hip_atomic_load(&slots[3], __ATOMIC_RELAXED, __HIP_MEMORY_SCOPE_AGENT);
                if (s0 + s1 + s2 + s3 == 4) break;
                __builtin_amdgcn_s_sleep(1);
            }
            (void)__hip_atomic_load(&slots[sl], __ATOMIC_ACQUIRE, __HIP_MEMORY_SCOPE_AGENT);
        }
        __syncthreads();   /* D: flags seen */

        /* rebuild foreign h slices: thread t -> k = t */
        int sk = tid >> 6, li = tid & 63;
        if (sk != sl) {
            const float* hp = hpub + (c * 2 + par) * NSL * 256 + sk * 256;
            float v0 = __hip_atomic_load(hp + 0 * 64 + li, __ATOMIC_RELAXED, __HIP_MEMORY_SCOPE_AGENT);
            float v1 = __hip_atomic_load(hp + 1 * 64 + li, __ATOMIC_RELAXED, __HIP_MEMORY_SCOPE_AGENT);
            float v2 = __hip_atomic_load(hp + 2 * 64 + li, __ATOMIC_RELAXED, __HIP_MEMORY_SCOPE_AGENT);
            float v3 = __hip_atomic_load(hp + 3 * 64 + li, __ATOMIC_RELAXED, __HIP_MEMORY_SCOPE_AGENT);
            hs4[tid] = make_float4(v0, v1, v2, v3);
        }
        /* barrier A (next iter) orders hs4 for readers */
    }

    /* final emission (step S-1) */
    __syncthreads();
    {
        int spe = d ? 0 : (S - 1);
        float h0 = hsf[(l +   0) * 4 + bq];
        float h1 = hsf[(l +  64) * 4 + bq];
        float h2 = hsf[(l + 128) * 4 + bq];
        float h3 = hsf[(l + 192) * 4 + bq];
        #pragma unroll
        for (int i = 0; i < 3; i++) {
            if (i < nt) {
                float v = h0 * mwreg[i][0] + h1 * mwreg[i][1]
                        + h2 * mwreg[i][2] + h3 * mwreg[i][3];
                v += __shfl_xor(v, 32, 64); v += __shfl_xor(v, 16, 64);
                v += __shfl_xor(v, 8, 64);  v += __shfl_xor(v, 4, 64);
                v += __shfl_xor(v, 2, 64);  v += __shfl_xor(v, 1, 64);
                if (l == 0)
                    emdst[((size_t)(b0 + bq) * S + spe) * T + (t0 + i)] = v;
            }
        }
    }
}

/* Viterbi forward: one wave per batch, lane t = tag. Strict-> ascending scan
   matches jnp.argmax first-index tie-breaking. */
__global__ __launch_bounds__(64) void k_vit(const int* __restrict__ data,
                                            const float* __restrict__ strans,
                                            const float* __restrict__ trans,
                                            const float* __restrict__ etrans,
                                            const float* __restrict__ mlpb,
                                            float* __restrict__ out,
                                            char* __restrict__ ws) {
    int b = blockIdx.x, t = threadIdx.x;
    const float* emf = (const float*)(ws + OFF_EMF);
    const float* emb = (const float*)(ws + OFF_EMB);
    char* bp = ws + OFF_BP;
    int*  lt = (int*)(ws + OFF_LT);
    bool act = t < T;

    float trp[T];
    float mb = 0.0f;
    if (act) {
        #pragma unroll
        for (int p = 0; p < T; p++) trp[p] = trans[p * T + t];
        mb = mlpb[t];
    }
    float score = -1e30f;
    if (act) score = strans[t] + emf[(b * S) * T + t] + emb[(b * S) * T + t] + mb;

    for (int s = 1; s < S; s++) {
        float e = 0.0f;
        if (act) e = emf[(b * S + s) * T + t] + emb[(b * S + s) * T + t] + mb;
        float best = __shfl(score, 0, 64) + trp[0];
        int bpi = 0;
        #pragma unroll
        for (int p = 1; p < T; p++) {
            float cand = __shfl(score, p, 64) + trp[p];
            if (cand > best) { best = cand; bpi = p; }
        }
        int m = data[b * S + s] != 0;
        if (act) {
            score = m ? (best + e) : score;
            bp[((size_t)(s - 1) * B + b) * 16 + t] = (char)bpi;
        }
    }
    float fin = act ? score + etrans[t] : -1e30f;
    float bv = __shfl(fin, 0, 64);
    int bi = 0;
    #pragma unroll
    for (int p = 1; p < T; p++) {
        float v = __shfl(fin, p, 64);
        if (v > bv) { bv = v; bi = p; }
    }
    if (t == 0) { out[B * S + b] = bv; lt[b] = bi; }
}

/* Backtrack: thread = batch; bp row address is tag-independent -> pipelined loads */
__global__ __launch_bounds__(128) void k_back(const int* __restrict__ data, char* __restrict__ ws) {
    int b = threadIdx.x;
    const int4* bp4 = (const int4*)(ws + OFF_BP);
    const int*  lt  = (const int*)(ws + OFF_LT);
    int* pt = (int*)(ws + OFF_PT);
    int tag = lt[b];
    pt[(S - 1) * B + b] = tag;
    for (int p = S - 2; p >= 0; p--) {
        int4 r = bp4[(size_t)p * B + b];
        int m = data[b * S + p + 1] != 0;
        unsigned w = (unsigned)(tag < 8 ? (tag < 4 ? r.x : r.y) : r.z);
        int nt = (int)((w >> ((tag & 3) * 8)) & 0xff);
        tag = m ? nt : tag;
        pt[p * B + b] = tag;
    }
}

/* paths -> float output with mask zeroing */
__global__ __launch_bounds__(256) void k_fin(const int* __restrict__ data,
                                             float* __restrict__ out,
                                             const char* __restrict__ ws) {
    int tid = blockIdx.x * 256 + threadIdx.x;   /* 65536 */
    const int* pt = (const int*)(ws + OFF_PT);
    int b = tid >> 9, p = tid & 511;
    out[tid] = (data[tid] != 0) ? (float)pt[p * B + b] : 0.0f;
}

extern "C" void kernel_launch(void* const* d_in, const int* in_sizes, int n_in,
                              void* d_out, int out_size, void* d_ws, size_t ws_size,
                              hipStream_t stream) {
    const int*   data = (const int*)d_in[0];
    /* d_in[1] = mask (bool) — unused; mask == (data != 0) */
    const float* emb  = (const float*)d_in[2];
    const float* wihf = (const float*)d_in[3];
    const float* whhf = (const float*)d_in[4];
    const float* bf   = (const float*)d_in[5];
    const float* wihb = (const float*)d_in[6];
    const float* whhb = (const float*)d_in[7];
    const float* bb   = (const float*)d_in[8];
    const float* mlpW = (const float*)d_in[9];
    const float* mlpb = (const float*)d_in[10];
    const float* st   = (const float*)d_in[11];
    const float* tr   = (const float*)d_in[12];
    const float* et   = (const float*)d_in[13];
    float* out = (float*)d_out;
    char*  ws  = (char*)d_ws;

    hipLaunchKernelGGL(k_zero, dim3(512),  dim3(256), 0, stream, ws);
    hipLaunchKernelGGL(k_pemb, dim3(750),  dim3(256), 0, stream, emb, wihf, bf, wihb, bb, ws);
    hipLaunchKernelGGL(k_lstm, dim3(256),  dim3(256), 0, stream, data, whhf, whhb, mlpW, ws);
    hipLaunchKernelGGL(k_vit,  dim3(128),  dim3(64),  0, stream, data, st, tr, et, mlpb, out, ws);
    hipLaunchKernelGGL(k_back, dim3(1),    dim3(128), 0, stream, data, ws);
    hipLaunchKernelGGL(k_fin,  dim3(256),  dim3(256), 0, stream, data, out, ws);
}

// Round 5
// 7202.940 us; speedup vs baseline: 1.3948x; 1.1058x over previous
//
#include <hip/hip_runtime.h>
#include <math.h>
#include <stdint.h>

#define B 128
#define S 512
#define V 6000
#define E 100
#define H 256
#define G4 1024   /* 4*H */
#define T 9

/* workspace byte offsets (256-aligned) */
#define OFF_PEMB_F 0u
#define PEMB_BYTES (V*G4*4u)                    /* 24,576,000 */
#define OFF_PEMB_B (OFF_PEMB_F + PEMB_BYTES)
#define OFF_EMF    (OFF_PEMB_B + PEMB_BYTES)    /* 49,152,000 */
#define EM_BYTES   (B*S*T*4u)                   /* 2,359,296 */
#define OFF_EMB    (OFF_EMF + EM_BYTES)
#define OFF_BP     (OFF_EMB + EM_BYTES)         /* 53,870,592 */
#define BP_BYTES   ((S-1)*B*16u)                /* 1,046,528 */
#define OFF_LT     (OFF_BP + BP_BYTES)
#define OFF_PT     (OFF_LT + 512u)
#define OFF_HPUB   (OFF_PT + B*S*4u)            /* 64c*2par*4sl*256 floats = 524,288 B */
#define OFF_CNT    (OFF_HPUB + 524288u)         /* 64c*512ss*4sl ints = 524,288 B */

#define FLAGPAT 0x0000000100000001ULL

__device__ __forceinline__ float sigf(float x) { return 1.0f / (1.0f + expf(-x)); }

__device__ __forceinline__ float2 pkfma(float s, float2 h, float2 a) {
    return make_float2(fmaf(s, h.x, a.x), fmaf(s, h.y, a.y));
}

/* flag counters -> 0 (ws re-poisoned to 0xAA each launch) */
__global__ __launch_bounds__(256) void k_zero(char* __restrict__ ws) {
    int i = blockIdx.x * 256 + threadIdx.x;     /* 512*256 = 131072 */
    ((int*)(ws + OFF_CNT))[i] = 0;
}

/* pemb[v][g4] = bias[g4] + sum_e emb[v][e] * W_ih[g4][e],  g4 = q*H + j */
__global__ __launch_bounds__(256) void k_pemb(const float* __restrict__ emb,
                                              const float* __restrict__ wf, const float* __restrict__ bf,
                                              const float* __restrict__ wb, const float* __restrict__ bb,
                                              char* __restrict__ ws) {
    int blk = blockIdx.x;                   /* 0..749 */
    int d   = blk >= 375;
    int vb  = d ? blk - 375 : blk;
    const float* W    = d ? wb : wf;
    const float* bias = d ? bb : bf;
    float* pe = (float*)(ws + (d ? OFF_PEMB_B : OFF_PEMB_F));

    __shared__ float es[16 * E];
    for (int i = threadIdx.x; i < 16 * E; i += 256) es[i] = emb[vb * 16 * E + i];
    __syncthreads();

    int j = threadIdx.x;
    float acc[4][16];
    #pragma unroll
    for (int q = 0; q < 4; q++) {
        float bq = bias[q * H + j];
        #pragma unroll
        for (int v = 0; v < 16; v++) acc[q][v] = bq;
    }
    for (int e = 0; e < E; e++) {
        float w0 = W[(0 * H + j) * E + e];
        float w1 = W[(1 * H + j) * E + e];
        float w2 = W[(2 * H + j) * E + e];
        float w3 = W[(3 * H + j) * E + e];
        #pragma unroll
        for (int v = 0; v < 16; v++) {
            float x = es[v * E + e];
            acc[0][v] += w0 * x; acc[1][v] += w1 * x;
            acc[2][v] += w2 * x; acc[3][v] += w3 * x;
        }
    }
    for (int v = 0; v < 16; v++)
        #pragma unroll
        for (int q = 0; q < 4; q++)
            pe[(vb * 16 + v) * G4 + q * H + j] = acc[q][v];
}

/* Cluster-of-4 LSTM v2. 256 blocks x 512 threads.
   blk: sl = blk>>6 (slice 0..3), c = blk&63 (cluster; stride-64 peers share an
   XCD under %8 round-robin). Cluster c: dir = c>>5, batches b0 = (c&31)*4..+3.
   Slice owns gate rows {q*256 + 64*sl + jl}. Thread t = (r = t&255, kh = t>>8):
   row g4(r), k-half kh -> 128 W floats in 32 float4 VGPRs (~190 VGPR total, NO
   spill -- R4's 256-cap spill was the 14.6us/step killer).
   Per step: FMA over own k-half (h broadcast from LDS), LDS partial merge
   (kh1->pbuf, kh0 sums -> gbuf), activation (thread<256 = (batch,unit)),
   h publish as 256 coalesced 4B IC stores, per-slice flag, poll via 2 u64
   loads, readback = 384 threads x one 8B atomic load, emission (tag-subset
   per slice) from the complete h. Exchange runs EVERY step (incl. last). */
__global__ __launch_bounds__(512) void k_lstm(const int* __restrict__ data,
                                              const float* __restrict__ whhf,
                                              const float* __restrict__ whhb,
                                              const float* __restrict__ mlpW,
                                              char* __restrict__ ws) {
    int blk = blockIdx.x;
    int sl = blk >> 6, c = blk & 63;
    int d = c >> 5, b0 = (c & 31) << 2;
    const float* pe = (const float*)(ws + (d ? OFF_PEMB_B : OFF_PEMB_F));
    float* emdst = (float*)(ws + (d ? OFF_EMB : OFF_EMF));
    float* hpubF = (float*)(ws + OFF_HPUB);
    int*   cnt   = (int*)(ws + OFF_CNT);

    __shared__ float  hsf[1024];     /* h: [j 256][b 4] */
    __shared__ float4 pbuf[256];     /* kh=1 partials per row r */
    __shared__ float4 gbuf[256];     /* merged gates per row r: (b0..b3) */
    const float* gbufF = (const float*)gbuf;

    int tid = threadIdx.x;
    int r = tid & 255, kh = tid >> 8;
    int q = r >> 6, jl = r & 63;
    int g4 = q * H + sl * 64 + jl;

    /* W half-row -> 32 float4 registers */
    const float* whh = d ? whhb : whhf;
    float4 w4[32];
    {
        const float4* wrow = (const float4*)(whh + (size_t)g4 * H + kh * 128);
        #pragma unroll
        for (int i = 0; i < 32; i++) w4[i] = wrow[i];
    }

    /* emission role (threads < 256): (eb = batch, el = lane-unit) */
    int eb = tid >> 6, el = tid & 63;
    int ntag = (sl == 0) ? 3 : 2;
    int t0   = (sl == 0) ? 0 : (2 * sl + 1);
    float mwreg[3][4];
    #pragma unroll
    for (int i = 0; i < 3; i++)
        if (i < ntag)
            #pragma unroll
            for (int jj = 0; jj < 4; jj++)
                mwreg[i][jj] = mlpW[(t0 + i) * (2 * H) + d * H + jj * 64 + el];

    hsf[tid] = 0.0f; hsf[tid + 512] = 0.0f;
    float cst = 0.0f;

    /* prefetch pemb for step 0 (kh0 waves only -- wave-uniform branch) */
    float pf0 = 0.f, pf1 = 0.f, pf2 = 0.f, pf3 = 0.f;
    if (kh == 0) {
        int sp0 = d ? (S - 1) : 0;
        pf0 = pe[(size_t)data[(b0 + 0) * S + sp0] * G4 + g4];
        pf1 = pe[(size_t)data[(b0 + 1) * S + sp0] * G4 + g4];
        pf2 = pe[(size_t)data[(b0 + 2) * S + sp0] * G4 + g4];
        pf3 = pe[(size_t)data[(b0 + 3) * S + sp0] * G4 + g4];
    }
    __syncthreads();

    for (int ss = 0; ss < S; ss++) {
        int sp = d ? (S - 1 - ss) : ss;
        int par = ss & 1;

        /* FMA over own k-half; batches packed (b0,b1),(b2,b3) */
        float2 a01, a23;
        if (kh == 0) { a01 = make_float2(pf0, pf1); a23 = make_float2(pf2, pf3); }
        else         { a01 = make_float2(0.f, 0.f); a23 = make_float2(0.f, 0.f); }
        if (kh == 0 && ss + 1 < S) {
            int spn = d ? (S - 2 - ss) : (ss + 1);
            pf0 = pe[(size_t)data[(b0 + 0) * S + spn] * G4 + g4];
            pf1 = pe[(size_t)data[(b0 + 1) * S + spn] * G4 + g4];
            pf2 = pe[(size_t)data[(b0 + 2) * S + spn] * G4 + g4];
            pf3 = pe[(size_t)data[(b0 + 3) * S + spn] * G4 + g4];
        }
        const float4* hq = (const float4*)hsf + (kh << 7);
        #pragma unroll
        for (int kk = 0; kk < 32; kk++) {
            float4 w  = w4[kk];
            float4 h0 = hq[kk * 4 + 0];
            float4 h1 = hq[kk * 4 + 1];
            float4 h2 = hq[kk * 4 + 2];
            float4 h3 = hq[kk * 4 + 3];
            a01 = pkfma(w.x, make_float2(h0.x, h0.y), a01);
            a23 = pkfma(w.x, make_float2(h0.z, h0.w), a23);
            a01 = pkfma(w.y, make_float2(h1.x, h1.y), a01);
            a23 = pkfma(w.y, make_float2(h1.z, h1.w), a23);
            a01 = pkfma(w.z, make_float2(h2.x, h2.y), a01);
            a23 = pkfma(w.z, make_float2(h2.z, h2.w), a23);
            a01 = pkfma(w.w, make_float2(h3.x, h3.y), a01);
            a23 = pkfma(w.w, make_float2(h3.z, h3.w), a23);
        }
        if (kh == 1) pbuf[r] = make_float4(a01.x, a01.y, a23.x, a23.y);
        __syncthreads();   /* B1: partials in pbuf */

        if (kh == 0) {
            float4 p = pbuf[r];
            gbuf[r] = make_float4(a01.x + p.x, a01.y + p.y, a23.x + p.z, a23.y + p.w);
        }
        __syncthreads();   /* B2: gates merged */

        /* activation: thread u<256 owns (batch ba = u>>6, unit j = 64*sl+la) */
        if (tid < 256) {
            int la = tid & 63, ba = tid >> 6;
            float gi = gbufF[(0 * 64 + la) * 4 + ba];
            float gf = gbufF[(1 * 64 + la) * 4 + ba];
            float gg = gbufF[(2 * 64 + la) * 4 + ba];
            float go = gbufF[(3 * 64 + la) * 4 + ba];
            float ig = sigf(gi), fg = sigf(gf), tg = tanhf(gg), og = sigf(go);
            cst = fg * cst + ig * tg;
            float hn = og * tanhf(cst);
            hsf[(sl * 64 + la) * 4 + ba] = hn;
            __hip_atomic_store(&hpubF[((c * 2 + par) * 4 + sl) * 256 + la * 4 + ba], hn,
                               __ATOMIC_RELAXED, __HIP_MEMORY_SCOPE_AGENT);
        }
        __syncthreads();   /* B3: publishes drained (vmcnt0 before barrier) */

        int* slots = cnt + (c * S + ss) * 4;
        if (tid == 0) {
            __hip_atomic_store(&slots[sl], 1, __ATOMIC_RELEASE, __HIP_MEMORY_SCOPE_AGENT);
            const unsigned long long* sv = (const unsigned long long*)slots;
            for (;;) {
                unsigned long long lo = __hip_atomic_load(&sv[0], __ATOMIC_RELAXED, __HIP_MEMORY_SCOPE_AGENT);
                unsigned long long hi = __hip_atomic_load(&sv[1], __ATOMIC_RELAXED, __HIP_MEMORY_SCOPE_AGENT);
                if (lo == FLAGPAT && hi == FLAGPAT) break;
                __builtin_amdgcn_s_sleep(1);
            }
            (void)__hip_atomic_load(&slots[0], __ATOMIC_ACQUIRE, __HIP_MEMORY_SCOPE_AGENT);
        }
        __syncthreads();   /* B4: all slices' h(ss) visible in IC */

        /* readback: 384 threads, one 8B atomic load each (3 foreign slices) */
        if (tid < 384) {
            int slf = (sl + 1 + (tid >> 7)) & 3;
            int i = tid & 127;   /* = jl*2 + pair */
            unsigned long long raw = __hip_atomic_load(
                (const unsigned long long*)(hpubF + ((c * 2 + par) * 4 + slf) * 256) + i,
                __ATOMIC_RELAXED, __HIP_MEMORY_SCOPE_AGENT);
            float2 v;
            v.x = __uint_as_float((unsigned)(raw & 0xffffffffu));
            v.y = __uint_as_float((unsigned)(raw >> 32));
            *(float2*)&hsf[slf * 256 + i * 2] = v;
        }
        __syncthreads();   /* B5: hsf = complete h(ss) */

        /* emission for position sp (dir-partial; tag subset per slice) */
        if (tid < 256) {
            float h0 = hsf[(el +   0) * 4 + eb];
            float h1 = hsf[(el +  64) * 4 + eb];
            float h2 = hsf[(el + 128) * 4 + eb];
            float h3 = hsf[(el + 192) * 4 + eb];
            #pragma unroll
            for (int i = 0; i < 3; i++) {
                if (i < ntag) {
                    float v = h0 * mwreg[i][0] + h1 * mwreg[i][1]
                            + h2 * mwreg[i][2] + h3 * mwreg[i][3];
                    v += __shfl_xor(v, 32, 64); v += __shfl_xor(v, 16, 64);
                    v += __shfl_xor(v, 8, 64);  v += __shfl_xor(v, 4, 64);
                    v += __shfl_xor(v, 2, 64);  v += __shfl_xor(v, 1, 64);
                    if (el == 0)
                        emdst[((size_t)(b0 + eb) * S + sp) * T + (t0 + i)] = v;
                }
            }
        }
        /* next iter FMA reads hsf; next writer (activation) is after next B2 */
    }
}

/* Viterbi forward: one wave per batch, lane t = tag. Strict-> ascending scan
   matches jnp.argmax first-index tie-breaking. */
__global__ __launch_bounds__(64) void k_vit(const int* __restrict__ data,
                                            const float* __restrict__ strans,
                                            const float* __restrict__ trans,
                                            const float* __restrict__ etrans,
                                            const float* __restrict__ mlpb,
                                            float* __restrict__ out,
                                            char* __restrict__ ws) {
    int b = blockIdx.x, t = threadIdx.x;
    const float* emf = (const float*)(ws + OFF_EMF);
    const float* emb = (const float*)(ws + OFF_EMB);
    char* bp = ws + OFF_BP;
    int*  lt = (int*)(ws + OFF_LT);
    bool act = t < T;

    float trp[T];
    float mb = 0.0f;
    if (act) {
        #pragma unroll
        for (int p = 0; p < T; p++) trp[p] = trans[p * T + t];
        mb = mlpb[t];
    }
    float score = -1e30f;
    if (act) score = strans[t] + emf[(b * S) * T + t] + emb[(b * S) * T + t] + mb;

    for (int s = 1; s < S; s++) {
        float e = 0.0f;
        if (act) e = emf[(b * S + s) * T + t] + emb[(b * S + s) * T + t] + mb;
        float best = __shfl(score, 0, 64) + trp[0];
        int bpi = 0;
        #pragma unroll
        for (int p = 1; p < T; p++) {
            float cand = __shfl(score, p, 64) + trp[p];
            if (cand > best) { best = cand; bpi = p; }
        }
        int m = data[b * S + s] != 0;
        if (act) {
            score = m ? (best + e) : score;
            bp[((size_t)(s - 1) * B + b) * 16 + t] = (char)bpi;
        }
    }
    float fin = act ? score + etrans[t] : -1e30f;
    float bv = __shfl(fin, 0, 64);
    int bi = 0;
    #pragma unroll
    for (int p = 1; p < T; p++) {
        float v = __shfl(fin, p, 64);
        if (v > bv) { bv = v; bi = p; }
    }
    if (t == 0) { out[B * S + b] = bv; lt[b] = bi; }
}

/* Backtrack: thread = batch; bp row address is tag-independent -> pipelined loads */
__global__ __launch_bounds__(128) void k_back(const int* __restrict__ data, char* __restrict__ ws) {
    int b = threadIdx.x;
    const int4* bp4 = (const int4*)(ws + OFF_BP);
    const int*  lt  = (const int*)(ws + OFF_LT);
    int* pt = (int*)(ws + OFF_PT);
    int tag = lt[b];
    pt[(S - 1) * B + b] = tag;
    for (int p = S - 2; p >= 0; p--) {
        int4 r = bp4[(size_t)p * B + b];
        int m = data[b * S + p + 1] != 0;
        unsigned w = (unsigned)(tag < 8 ? (tag < 4 ? r.x : r.y) : r.z);
        int nt = (int)((w >> ((tag & 3) * 8)) & 0xff);
        tag = m ? nt : tag;
        pt[p * B + b] = tag;
    }
}

/* paths -> float output with mask zeroing */
__global__ __launch_bounds__(256) void k_fin(const int* __restrict__ data,
                                             float* __restrict__ out,
                                             const char* __restrict__ ws) {
    int tid = blockIdx.x * 256 + threadIdx.x;   /* 65536 */
    const int* pt = (const int*)(ws + OFF_PT);
    int b = tid >> 9, p = tid & 511;
    out[tid] = (data[tid] != 0) ? (float)pt[p * B + b] : 0.0f;
}

extern "C" void kernel_launch(void* const* d_in, const int* in_sizes, int n_in,
                              void* d_out, int out_size, void* d_ws, size_t ws_size,
                              hipStream_t stream) {
    const int*   data = (const int*)d_in[0];
    /* d_in[1] = mask (bool) — unused; mask == (data != 0) */
    const float* emb  = (const float*)d_in[2];
    const float* wihf = (const float*)d_in[3];
    const float* whhf = (const float*)d_in[4];
    const float* bf   = (const float*)d_in[5];
    const float* wihb = (const float*)d_in[6];
    const float* whhb = (const float*)d_in[7];
    const float* bb   = (const float*)d_in[8];
    const float* mlpW = (const float*)d_in[9];
    const float* mlpb = (const float*)d_in[10];
    const float* st   = (const float*)d_in[11];
    const float* tr   = (const float*)d_in[12];
    const float* et   = (const float*)d_in[13];
    float* out = (float*)d_out;
    char*  ws  = (char*)d_ws;

    hipLaunchKernelGGL(k_zero, dim3(512),  dim3(256), 0, stream, ws);
    hipLaunchKernelGGL(k_pemb, dim3(750),  dim3(256), 0, stream, emb, wihf, bf, wihb, bb, ws);
    hipLaunchKernelGGL(k_lstm, dim3(256),  dim3(512), 0, stream, data, whhf, whhb, mlpW, ws);
    hipLaunchKernelGGL(k_vit,  dim3(128),  dim3(64),  0, stream, data, st, tr, et, mlpb, out, ws);
    hipLaunchKernelGGL(k_back, dim3(1),    dim3(128), 0, stream, data, ws);
    hipLaunchKernelGGL(k_fin,  dim3(256),  dim3(256), 0, stream, data, out, ws);
}